// Round 23
// baseline (123.690 us; speedup 1.0000x reference)
//
#include <hip/hip_runtime.h>
#include <hip/hip_bf16.h>

#define S_LEN 2048
#define EMB 768
#define NH 12
#define HD 64
#define L2E 1.44269504088896340736f

typedef __attribute__((ext_vector_type(8))) short short8;
typedef __attribute__((ext_vector_type(4))) float f32x4;

typedef __attribute__((address_space(3))) void lds_t;
typedef __attribute__((address_space(1))) const void gbl_t;

__device__ __forceinline__ void gload16(const void* g, void* l) {
  __builtin_amdgcn_global_load_lds((gbl_t*)g, (lds_t*)l, 16, 0, 0);
}

__device__ __forceinline__ short f2bf(float f) {
  union { float f; unsigned u; } v; v.f = f;
  unsigned r = v.u + 0x7FFFu + ((v.u >> 16) & 1u);
  return (short)(r >> 16);
}

__device__ __forceinline__ unsigned pkbf(float a, float b) {
  unsigned r;
  asm("v_cvt_pk_bf16_f32 %0, %1, %2" : "=v"(r) : "v"(a), "v"(b));
  return r;
}

// fused input + weight conversion (single launch)
__global__ void cvt_all(const float* __restrict__ x,
                        const float* __restrict__ Wq, const float* __restrict__ Wk,
                        const float* __restrict__ Wv, const float* __restrict__ Wo,
                        short* __restrict__ xb, short* __restrict__ Wb,
                        short* __restrict__ Wob) {
  int bid = blockIdx.x, tid = threadIdx.x;
  const float* src;
  short* dst;
  int off;
  if (bid < 3072) {
    src = x; dst = xb; off = bid * 1024 + tid * 4;
  } else {
    int wb = bid - 3072;
    int sec = wb / 576;
    off = (wb % 576) * 1024 + tid * 4;
    src = sec == 0 ? Wq : sec == 1 ? Wk : sec == 2 ? Wv : Wo;
    dst = sec < 3 ? Wb + sec * 589824 : Wob;
  }
  float4 v = *reinterpret_cast<const float4*>(src + off);
  short4 o;
  o.x = f2bf(v.x); o.y = f2bf(v.y); o.z = f2bf(v.z); o.w = f2bf(v.w);
  *reinterpret_cast<short4*>(dst + off) = o;
}

// NT GEMM (R21 proven): dbuf global_load_lds + XOR swizzle + counted-vmcnt +
// LDS-coalesced MODE0 epilogue.
template<int MODE>
__global__ __launch_bounds__(256)
void gemm_nt(const short* __restrict__ A, const short* __restrict__ B,
             float* __restrict__ outk, float* __restrict__ outv,
             short* __restrict__ qb, short* __restrict__ kb, short* __restrict__ vtb,
             float* __restrict__ outp, const float* __restrict__ bias) {
  const int K = EMB;
  const int NT = K / 64;
  __shared__ __align__(16) char RAW[128 * 132 * 4];   // 67.6 KB
  short (*As)[128][64] = (short(*)[128][64])RAW;
  short (*Bs)[128][64] = (short(*)[128][64])(RAW + 32768);
  float (*Cl)[132] = (float(*)[132])RAW;
  int tid = threadIdx.x;
  int lane = tid & 63, wid = tid >> 6;
  int wm = wid >> 1, wn = wid & 1;
  int r16 = lane & 15, g4 = lane >> 4;
  int m0 = blockIdx.y * 128, n0 = blockIdx.x * 128;
  int lrow = lane >> 3, lchunk = lane & 7;
  int lcolsw = ((lchunk ^ lrow) * 8);
  f32x4 acc[4][4] = {};

#define STAGEG(BUF, K0) do {                                          \
    _Pragma("unroll")                                                 \
    for (int i = 0; i < 4; i++) {                                     \
      int r = wid * 32 + i * 8 + lrow;                                \
      gload16(A + (long)(m0 + r) * K + (K0) + lcolsw, &As[BUF][r][lchunk * 8]); \
      gload16(B + (long)(n0 + r) * K + (K0) + lcolsw, &Bs[BUF][r][lchunk * 8]); \
    } } while (0)

  STAGEG(0, 0);
  int cur = 0;
  for (int t = 0; t < NT; t++) {
    if (t + 1 < NT) {
      STAGEG(cur ^ 1, (t + 1) * 64);
      asm volatile("s_waitcnt vmcnt(8)" ::: "memory");
    } else {
      asm volatile("s_waitcnt vmcnt(0)" ::: "memory");
    }
    __builtin_amdgcn_sched_barrier(0);
    __builtin_amdgcn_s_barrier();
    __builtin_amdgcn_sched_barrier(0);
#pragma unroll
    for (int s = 0; s < 2; s++) {
      int csw = ((s * 4 + g4) ^ (r16 & 7)) * 8;
      short8 af[4], bf[4];
#pragma unroll
      for (int tt = 0; tt < 4; tt++) {
        af[tt] = *reinterpret_cast<const short8*>(&As[cur][wm * 64 + tt * 16 + r16][csw]);
        bf[tt] = *reinterpret_cast<const short8*>(&Bs[cur][wn * 64 + tt * 16 + r16][csw]);
      }
#pragma unroll
      for (int mt = 0; mt < 4; mt++)
#pragma unroll
        for (int nt = 0; nt < 4; nt++)
          acc[mt][nt] = __builtin_amdgcn_mfma_f32_16x16x32_bf16(af[mt], bf[nt], acc[mt][nt], 0, 0, 0);
    }
    __builtin_amdgcn_sched_barrier(0);
    __builtin_amdgcn_s_barrier();
    cur ^= 1;
  }
#undef STAGEG

  if (MODE == 1) {
#pragma unroll
    for (int mt = 0; mt < 4; mt++) {
      int nbase = m0 + wm * 64 + mt * 16 + g4 * 4;
#pragma unroll
      for (int nt = 0; nt < 4; nt++) {
        int f = n0 + wn * 64 + nt * 16 + r16;
#pragma unroll
        for (int r = 0; r < 4; r++)
          outp[(long)(nbase + r) * EMB + f] = acc[mt][nt][r] + bias[f];
      }
    }
    return;
  }

  const int bx = blockIdx.x;
  const int sec = bx / 6;
  const int h0 = (bx % 6) * 2;
  const int b = m0 >> 11, s0l = m0 & 2047;

  if (sec == 2) {
#pragma unroll
    for (int mt = 0; mt < 4; mt++) {
      int sg = s0l + wm * 64 + mt * 16 + g4 * 4;
#pragma unroll
      for (int nt = 0; nt < 4; nt++) {
        int fl = wn * 64 + nt * 16 + r16;
        int h = h0 + (fl >> 6), d = fl & 63;
        int bh = b * NH + h;
        short4 o;
        o.x = f2bf(acc[mt][nt][0]); o.y = f2bf(acc[mt][nt][1]);
        o.z = f2bf(acc[mt][nt][2]); o.w = f2bf(acc[mt][nt][3]);
        *reinterpret_cast<short4*>(
            &vtb[((long)(bh * 32 + (sg >> 6)) * 64 + d) * 64 + (sg & 63)]) = o;
      }
    }
  }

#pragma unroll
  for (int mt = 0; mt < 4; mt++) {
    int rl = wm * 64 + mt * 16 + g4 * 4;
#pragma unroll
    for (int nt = 0; nt < 4; nt++) {
      int fl = wn * 64 + nt * 16 + r16;
#pragma unroll
      for (int r = 0; r < 4; r++) Cl[rl + r][fl] = acc[mt][nt][r];
    }
  }
  __syncthreads();

  {
    int row = tid >> 1, cb = (tid & 1) * 32;
#pragma unroll
    for (int hh = 0; hh < 2; hh++) {
      const float* src = &Cl[row][hh * 64 + cb];
      long base = ((long)(b * NH + h0 + hh) * S_LEN + s0l) * HD + (long)row * 64 + cb;
      if (sec == 0) {
        short* dq = qb + base;
#pragma unroll
        for (int c = 0; c < 4; c++) {
          f32x4 a = *reinterpret_cast<const f32x4*>(src + c * 8);
          f32x4 bb = *reinterpret_cast<const f32x4*>(src + c * 8 + 4);
          short8 o;
#pragma unroll
          for (int j = 0; j < 4; j++) { o[j] = f2bf(a[j]); o[4 + j] = f2bf(bb[j]); }
          *reinterpret_cast<short8*>(dq + c * 8) = o;
        }
      } else if (sec == 1) {
        float* dk = outk + base;
        short* dkb = kb + base;
#pragma unroll
        for (int c = 0; c < 4; c++) {
          f32x4 a = *reinterpret_cast<const f32x4*>(src + c * 8);
          f32x4 bb = *reinterpret_cast<const f32x4*>(src + c * 8 + 4);
          *reinterpret_cast<f32x4*>(dk + c * 8) = a;
          *reinterpret_cast<f32x4*>(dk + c * 8 + 4) = bb;
          short8 o;
#pragma unroll
          for (int j = 0; j < 4; j++) { o[j] = f2bf(a[j]); o[4 + j] = f2bf(bb[j]); }
          *reinterpret_cast<short8*>(dkb + c * 8) = o;
        }
      } else {
        float* dv = outv + base;
#pragma unroll
        for (int c = 0; c < 8; c++)
          *reinterpret_cast<f32x4*>(dv + c * 4) =
              *reinterpret_cast<const f32x4*>(src + c * 4);
      }
    }
  }
}

// Flash attention v17: v16 math (2 waves x 32 q-rows, 2x LDS amortization)
// with SINGLE-buffered KV staging: LDS 26KB -> 6 blocks/CU x 2 waves =
// 12 waves/CU (v16's occupancy collapse fixed). Loop: STAGE -> syncthreads
// (vmcnt drain) -> compute -> syncthreads; stage latency hidden by
// block-level TLP (3 waves/SIMD at different phases).
__global__ __launch_bounds__(128)
void flash_attn17(const short* __restrict__ qb, const short* __restrict__ kb,
                  const short* __restrict__ vtb, short* __restrict__ mb) {
  const int tid = threadIdx.x;
  const int w = tid >> 6, lane = tid & 63;
  const int r16 = lane & 15, g4 = lane >> 4;
  const int id = blockIdx.x;
  const int xcd = id & 7, u = id >> 3;        // u in [0,96)
  const int bh = xcd + 8 * (u % 3);
  const int qt = 31 - u / 3;                  // longest first
  const int q0 = qt * 64 + w * 32;            // this wave's 32 q-rows
  const int nkt = qt + 1;                     // 64-row KV tiles (uniform, both waves)

  const short* qh = qb + (long)bh * S_LEN * HD;
  const short* kh = kb + (long)bh * S_LEN * HD;
  const short* vh = vtb + (long)bh * S_LEN * HD;  // [32 kt][64 d][64 k]

  __shared__ __align__(16) char RAW[26112];
  short (*KVl)[64][64] = (short(*)[64][64])RAW;                // [K|V][64][64] 16KB
  short (*Pa)[32][36] = (short(*)[32][36])(RAW + 16384);       // [2][32][36]
  short (*Pb)[32][36] = (short(*)[32][36])(RAW + 16384 + 4608);
  float (*sca_lds)[32] = (float(*)[32])(RAW + 25600);          // [2][32]

  // Staging: 128 threads; thread tid covers rows srow+16j (j=0..3), chunk tid&7.
  // Per load-group dst = wavebase + lane*16 (lane-linear: HW-legal).
  // Source column pre-swizzled (chunk ^ (row&7)); (srow+16j)&7 == srow&7.
  const int srow = tid >> 3, schunk = tid & 7;
  const short* ksrc = kh + srow * HD + ((schunk ^ (srow & 7)) * 8);
  const short* vsrc = vh + srow * 64 + ((schunk ^ (srow & 7)) * 8);
#define STAGE(KT) do {                                                   \
    long _off = (long)(KT) * 4096;                                       \
    _Pragma("unroll")                                                    \
    for (int j = 0; j < 4; j++) {                                        \
      gload16(ksrc + _off + j * 16 * HD, &KVl[0][srow + 16 * j][schunk * 8]); \
      gload16(vsrc + _off + j * 16 * 64, &KVl[1][srow + 16 * j][schunk * 8]); \
    } } while (0)

  short8 qf[2][2];
#pragma unroll
  for (int ct = 0; ct < 2; ct++)
#pragma unroll
    for (int ksl = 0; ksl < 2; ksl++)
      qf[ct][ksl] = *reinterpret_cast<const short8*>(
          qh + (q0 + ct * 16 + r16) * HD + ksl * 32 + g4 * 8);

  float m[2] = {-1e30f, -1e30f}, m2[2] = {-1.44e30f, -1.44e30f};
  float l[2] = {0.f, 0.f};                    // per-lane partials
  f32x4 oacc[2][4] = {};

  const int kc0 = (g4 ^ (r16 & 7)) * 8;       // swizzled chunk offset (shorts)

  for (int kt = 0; kt < nkt; kt++) {
    STAGE(kt);
    __syncthreads();  // drains vmcnt: KV tile resident; all threads past

    const short* kbuf = &KVl[0][0][0];
    const short* vbuf = &KVl[1][0][0];

    // K fragments (8 reads) -> QK^T: s[kb][ct], 16 MFMA
    f32x4 s[4][2] = {};
#pragma unroll
    for (int kb = 0; kb < 4; kb++) {
      short8 k0 = *reinterpret_cast<const short8*>(kbuf + (kb * 16 + r16) * 64 + kc0);
      short8 k1 = *reinterpret_cast<const short8*>(kbuf + (kb * 16 + r16) * 64 + (kc0 ^ 32));
#pragma unroll
      for (int ct = 0; ct < 2; ct++) {
        s[kb][ct] = __builtin_amdgcn_mfma_f32_16x16x32_bf16(k0, qf[ct][0], s[kb][ct], 0, 0, 0);
        s[kb][ct] = __builtin_amdgcn_mfma_f32_16x16x32_bf16(k1, qf[ct][1], s[kb][ct], 0, 0, 0);
      }
    }

    if (kt == nkt - 1) {  // diagonal tile: mask k > q (global indices)
#pragma unroll
      for (int ct = 0; ct < 2; ct++) {
        int qg = q0 + ct * 16 + r16;
#pragma unroll
        for (int kb = 0; kb < 4; kb++)
#pragma unroll
          for (int r = 0; r < 4; r++)
            if (kt * 64 + kb * 16 + g4 * 4 + r > qg) s[kb][ct][r] = -1e30f;
      }
    }

    float rm[2];
#pragma unroll
    for (int ct = 0; ct < 2; ct++) {
      float a = fmaxf(fmaxf(s[0][ct][0], s[0][ct][1]), fmaxf(s[0][ct][2], s[0][ct][3]));
      float b = fmaxf(fmaxf(s[1][ct][0], s[1][ct][1]), fmaxf(s[1][ct][2], s[1][ct][3]));
      float c = fmaxf(fmaxf(s[2][ct][0], s[2][ct][1]), fmaxf(s[2][ct][2], s[2][ct][3]));
      float d = fmaxf(fmaxf(s[3][ct][0], s[3][ct][1]), fmaxf(s[3][ct][2], s[3][ct][3]));
      rm[ct] = fmaxf(fmaxf(a, b), fmaxf(c, d));
    }

    bool cond = (rm[0] <= m[0] + 8.f) && (rm[1] <= m[1] + 8.f);
    if (!__all(cond)) {
      float sca[2];
#pragma unroll
      for (int ct = 0; ct < 2; ct++) {
        float x = rm[ct];
        x = fmaxf(x, __shfl_xor(x, 16));
        x = fmaxf(x, __shfl_xor(x, 32));
        float nm = fmaxf(m[ct], x);
        sca[ct] = __builtin_exp2f((m[ct] - nm) * L2E);
        m[ct] = nm; m2[ct] = nm * L2E; l[ct] *= sca[ct];
      }
      if (g4 == 0) { sca_lds[w][r16] = sca[0]; sca_lds[w][16 + r16] = sca[1]; }
      f32x4 sr0 = *reinterpret_cast<const f32x4*>(&sca_lds[w][g4 * 4]);
      f32x4 sr1 = *reinterpret_cast<const f32x4*>(&sca_lds[w][16 + g4 * 4]);
#pragma unroll
      for (int dt = 0; dt < 4; dt++)
#pragma unroll
        for (int r = 0; r < 4; r++) {
          oacc[0][dt][r] *= sr0[r];
          oacc[1][dt][r] *= sr1[r];
        }
    }

    float rs[2] = {0.f, 0.f};
#pragma unroll
    for (int kb = 0; kb < 4; kb++)
#pragma unroll
      for (int ct = 0; ct < 2; ct++)
#pragma unroll
        for (int r = 0; r < 4; r++) {
          s[kb][ct][r] = __builtin_exp2f(fmaf(s[kb][ct][r], L2E, -m2[ct]));
          rs[ct] += s[kb][ct][r];
        }
    l[0] += rs[0]; l[1] += rs[1];

    // P -> LDS (k 0..31 in Pa, 32..63 in Pb)
#pragma unroll
    for (int kb = 0; kb < 4; kb++)
#pragma unroll
      for (int ct = 0; ct < 2; ct++) {
        uint2 wv;
        wv.x = pkbf(s[kb][ct][0], s[kb][ct][1]);
        wv.y = pkbf(s[kb][ct][2], s[kb][ct][3]);
        short* dstp = (kb < 2) ? &Pa[w][ct * 16 + r16][(kb & 1) * 16 + g4 * 4]
                               : &Pb[w][ct * 16 + r16][(kb & 1) * 16 + g4 * 4];
        *reinterpret_cast<uint2*>(dstp) = wv;
      }
    short8 pa[2][2];
#pragma unroll
    for (int ct = 0; ct < 2; ct++) {
      pa[ct][0] = *reinterpret_cast<const short8*>(&Pa[w][ct * 16 + r16][g4 * 8]);
      pa[ct][1] = *reinterpret_cast<const short8*>(&Pb[w][ct * 16 + r16][g4 * 8]);
    }

    // V fragments (8 reads) -> PV: 16 MFMA
#pragma unroll
    for (int dt = 0; dt < 4; dt++) {
      short8 v0 = *reinterpret_cast<const short8*>(vbuf + (dt * 16 + r16) * 64 + kc0);
      short8 v1 = *reinterpret_cast<const short8*>(vbuf + (dt * 16 + r16) * 64 + (kc0 ^ 32));
#pragma unroll
      for (int ct = 0; ct < 2; ct++) {
        oacc[ct][dt] = __builtin_amdgcn_mfma_f32_16x16x32_bf16(pa[ct][0], v0, oacc[ct][dt], 0, 0, 0);
        oacc[ct][dt] = __builtin_amdgcn_mfma_f32_16x16x32_bf16(pa[ct][1], v1, oacc[ct][dt], 0, 0, 0);
      }
    }

    __syncthreads();  // all waves done reading KVl before next STAGE overwrites
  }
#undef STAGE

  // ---- epilogue ----
#pragma unroll
  for (int ct = 0; ct < 2; ct++) {
    float rsv = l[ct];
    rsv += __shfl_xor(rsv, 16);
    rsv += __shfl_xor(rsv, 32);
    if (g4 == 0) sca_lds[w][ct * 16 + r16] = rsv;
  }
  f32x4 li0 = *reinterpret_cast<const f32x4*>(&sca_lds[w][g4 * 4]);
  f32x4 li1 = *reinterpret_cast<const f32x4*>(&sca_lds[w][16 + g4 * 4]);
  f32x4 iv0, iv1;
#pragma unroll
  for (int r = 0; r < 4; r++) { iv0[r] = 1.f / li0[r]; iv1[r] = 1.f / li1[r]; }

  float* Ow = (float*)(RAW + w * 32 * 68 * 4);   // [32][68] per wave (aliases KVl/Pa)
#pragma unroll
  for (int dt = 0; dt < 4; dt++)
#pragma unroll
    for (int r = 0; r < 4; r++) {
      Ow[(g4 * 4 + r) * 68 + dt * 16 + r16] = oacc[0][dt][r] * iv0[r];
      Ow[(16 + g4 * 4 + r) * 68 + dt * 16 + r16] = oacc[1][dt][r] * iv1[r];
    }
  {
    int row = lane >> 1, cb = (lane & 1) * 32;
    int bb = bh / NH, h = bh % NH;
    const float* src = &Ow[row * 68 + cb];
    short* dst = &mb[((long)(bb * S_LEN + q0 + row)) * EMB + h * HD + cb];
#pragma unroll
    for (int c = 0; c < 4; c++) {
      f32x4 a = *reinterpret_cast<const f32x4*>(src + c * 8);
      f32x4 b2 = *reinterpret_cast<const f32x4*>(src + c * 8 + 4);
      short8 o;
#pragma unroll
      for (int j = 0; j < 4; j++) { o[j] = f2bf(a[j]); o[4 + j] = f2bf(b2[j]); }
      *reinterpret_cast<short8*>(dst + c * 8) = o;
    }
  }
}

extern "C" void kernel_launch(void* const* d_in, const int* in_sizes, int n_in,
                              void* d_out, int out_size, void* d_ws, size_t ws_size,
                              hipStream_t stream) {
  const float* x  = (const float*)d_in[0];
  const float* Wq = (const float*)d_in[1];
  const float* Wk = (const float*)d_in[2];
  const float* Wv = (const float*)d_in[3];
  const float* Wo = (const float*)d_in[4];
  const float* bo = (const float*)d_in[5];

  float* out  = (float*)d_out;
  float* outk = out + 3145728;
  float* outv = out + 6291456;

  short* ws  = (short*)d_ws;
  short* xb  = ws;                 // [4096][768]
  short* Wb  = xb + 3145728;       // [2304][768]  (Wq;Wk;Wv)
  short* Wob = Wb + 1769472;       // [768][768]
  short* qb  = Wob + 589824;       // [24][2048][64]
  short* kb  = qb + 3145728;       // [24][2048][64]
  short* vtb = kb + 3145728;       // [24][32][64][64]  (V tiled per 64-row KV tile)
  short* mb  = vtb + 3145728;      // [4096][768]    merged attn, bf16

  cvt_all<<<5376, 256, 0, stream>>>(x, Wq, Wk, Wv, Wo, xb, Wb, Wob);

  gemm_nt<0><<<dim3(18, 32), 256, 0, stream>>>(xb, Wb, outk, outv, qb, kb, vtb, nullptr, nullptr);
  flash_attn17<<<768, 128, 0, stream>>>(qb, kb, vtb, mb);
  gemm_nt<1><<<dim3(6, 32), 256, 0, stream>>>(mb, Wob, nullptr, nullptr, nullptr, nullptr, nullptr, out, bo);
}

// Round 24
// 103.934 us; speedup vs baseline: 1.1901x; 1.1901x over previous
//
#include <hip/hip_runtime.h>
#include <hip/hip_bf16.h>

#define S_LEN 2048
#define EMB 768
#define NH 12
#define HD 64
#define L2E 1.44269504088896340736f

typedef __attribute__((ext_vector_type(8))) short short8;
typedef __attribute__((ext_vector_type(4))) float f32x4;

typedef __attribute__((address_space(3))) void lds_t;
typedef __attribute__((address_space(1))) const void gbl_t;

__device__ __forceinline__ void gload16(const void* g, void* l) {
  __builtin_amdgcn_global_load_lds((gbl_t*)g, (lds_t*)l, 16, 0, 0);
}

__device__ __forceinline__ short f2bf(float f) {
  union { float f; unsigned u; } v; v.f = f;
  unsigned r = v.u + 0x7FFFu + ((v.u >> 16) & 1u);
  return (short)(r >> 16);
}

__device__ __forceinline__ unsigned pkbf(float a, float b) {
  unsigned r;
  asm("v_cvt_pk_bf16_f32 %0, %1, %2" : "=v"(r) : "v"(a), "v"(b));
  return r;
}

// fused input + weight conversion (single launch)
__global__ void cvt_all(const float* __restrict__ x,
                        const float* __restrict__ Wq, const float* __restrict__ Wk,
                        const float* __restrict__ Wv, const float* __restrict__ Wo,
                        short* __restrict__ xb, short* __restrict__ Wb,
                        short* __restrict__ Wob) {
  int bid = blockIdx.x, tid = threadIdx.x;
  const float* src;
  short* dst;
  int off;
  if (bid < 3072) {
    src = x; dst = xb; off = bid * 1024 + tid * 4;
  } else {
    int wb = bid - 3072;
    int sec = wb / 576;
    off = (wb % 576) * 1024 + tid * 4;
    src = sec == 0 ? Wq : sec == 1 ? Wk : sec == 2 ? Wv : Wo;
    dst = sec < 3 ? Wb + sec * 589824 : Wob;
  }
  float4 v = *reinterpret_cast<const float4*>(src + off);
  short4 o;
  o.x = f2bf(v.x); o.y = f2bf(v.y); o.z = f2bf(v.z); o.w = f2bf(v.w);
  *reinterpret_cast<short4*>(dst + off) = o;
}

// NT GEMM (R21 proven): dbuf global_load_lds + XOR swizzle + counted-vmcnt +
// LDS-coalesced MODE0 epilogue.
template<int MODE>
__global__ __launch_bounds__(256)
void gemm_nt(const short* __restrict__ A, const short* __restrict__ B,
             float* __restrict__ outk, float* __restrict__ outv,
             short* __restrict__ qb, short* __restrict__ kb, short* __restrict__ vtb,
             float* __restrict__ outp, const float* __restrict__ bias) {
  const int K = EMB;
  const int NT = K / 64;
  __shared__ __align__(16) char RAW[128 * 132 * 4];   // 67.6 KB
  short (*As)[128][64] = (short(*)[128][64])RAW;
  short (*Bs)[128][64] = (short(*)[128][64])(RAW + 32768);
  float (*Cl)[132] = (float(*)[132])RAW;
  int tid = threadIdx.x;
  int lane = tid & 63, wid = tid >> 6;
  int wm = wid >> 1, wn = wid & 1;
  int r16 = lane & 15, g4 = lane >> 4;
  int m0 = blockIdx.y * 128, n0 = blockIdx.x * 128;
  int lrow = lane >> 3, lchunk = lane & 7;
  int lcolsw = ((lchunk ^ lrow) * 8);
  f32x4 acc[4][4] = {};

#define STAGEG(BUF, K0) do {                                          \
    _Pragma("unroll")                                                 \
    for (int i = 0; i < 4; i++) {                                     \
      int r = wid * 32 + i * 8 + lrow;                                \
      gload16(A + (long)(m0 + r) * K + (K0) + lcolsw, &As[BUF][r][lchunk * 8]); \
      gload16(B + (long)(n0 + r) * K + (K0) + lcolsw, &Bs[BUF][r][lchunk * 8]); \
    } } while (0)

  STAGEG(0, 0);
  int cur = 0;
  for (int t = 0; t < NT; t++) {
    if (t + 1 < NT) {
      STAGEG(cur ^ 1, (t + 1) * 64);
      asm volatile("s_waitcnt vmcnt(8)" ::: "memory");
    } else {
      asm volatile("s_waitcnt vmcnt(0)" ::: "memory");
    }
    __builtin_amdgcn_sched_barrier(0);
    __builtin_amdgcn_s_barrier();
    __builtin_amdgcn_sched_barrier(0);
#pragma unroll
    for (int s = 0; s < 2; s++) {
      int csw = ((s * 4 + g4) ^ (r16 & 7)) * 8;
      short8 af[4], bf[4];
#pragma unroll
      for (int tt = 0; tt < 4; tt++) {
        af[tt] = *reinterpret_cast<const short8*>(&As[cur][wm * 64 + tt * 16 + r16][csw]);
        bf[tt] = *reinterpret_cast<const short8*>(&Bs[cur][wn * 64 + tt * 16 + r16][csw]);
      }
#pragma unroll
      for (int mt = 0; mt < 4; mt++)
#pragma unroll
        for (int nt = 0; nt < 4; nt++)
          acc[mt][nt] = __builtin_amdgcn_mfma_f32_16x16x32_bf16(af[mt], bf[nt], acc[mt][nt], 0, 0, 0);
    }
    __builtin_amdgcn_sched_barrier(0);
    __builtin_amdgcn_s_barrier();
    cur ^= 1;
  }
#undef STAGEG

  if (MODE == 1) {
#pragma unroll
    for (int mt = 0; mt < 4; mt++) {
      int nbase = m0 + wm * 64 + mt * 16 + g4 * 4;
#pragma unroll
      for (int nt = 0; nt < 4; nt++) {
        int f = n0 + wn * 64 + nt * 16 + r16;
#pragma unroll
        for (int r = 0; r < 4; r++)
          outp[(long)(nbase + r) * EMB + f] = acc[mt][nt][r] + bias[f];
      }
    }
    return;
  }

  const int bx = blockIdx.x;
  const int sec = bx / 6;
  const int h0 = (bx % 6) * 2;
  const int b = m0 >> 11, s0l = m0 & 2047;

  if (sec == 2) {
#pragma unroll
    for (int mt = 0; mt < 4; mt++) {
      int sg = s0l + wm * 64 + mt * 16 + g4 * 4;
#pragma unroll
      for (int nt = 0; nt < 4; nt++) {
        int fl = wn * 64 + nt * 16 + r16;
        int h = h0 + (fl >> 6), d = fl & 63;
        int bh = b * NH + h;
        short4 o;
        o.x = f2bf(acc[mt][nt][0]); o.y = f2bf(acc[mt][nt][1]);
        o.z = f2bf(acc[mt][nt][2]); o.w = f2bf(acc[mt][nt][3]);
        *reinterpret_cast<short4*>(
            &vtb[((long)(bh * 32 + (sg >> 6)) * 64 + d) * 64 + (sg & 63)]) = o;
      }
    }
  }

#pragma unroll
  for (int mt = 0; mt < 4; mt++) {
    int rl = wm * 64 + mt * 16 + g4 * 4;
#pragma unroll
    for (int nt = 0; nt < 4; nt++) {
      int fl = wn * 64 + nt * 16 + r16;
#pragma unroll
      for (int r = 0; r < 4; r++) Cl[rl + r][fl] = acc[mt][nt][r];
    }
  }
  __syncthreads();

  {
    int row = tid >> 1, cb = (tid & 1) * 32;
#pragma unroll
    for (int hh = 0; hh < 2; hh++) {
      const float* src = &Cl[row][hh * 64 + cb];
      long base = ((long)(b * NH + h0 + hh) * S_LEN + s0l) * HD + (long)row * 64 + cb;
      if (sec == 0) {
        short* dq = qb + base;
#pragma unroll
        for (int c = 0; c < 4; c++) {
          f32x4 a = *reinterpret_cast<const f32x4*>(src + c * 8);
          f32x4 bb = *reinterpret_cast<const f32x4*>(src + c * 8 + 4);
          short8 o;
#pragma unroll
          for (int j = 0; j < 4; j++) { o[j] = f2bf(a[j]); o[4 + j] = f2bf(bb[j]); }
          *reinterpret_cast<short8*>(dq + c * 8) = o;
        }
      } else if (sec == 1) {
        float* dk = outk + base;
        short* dkb = kb + base;
#pragma unroll
        for (int c = 0; c < 4; c++) {
          f32x4 a = *reinterpret_cast<const f32x4*>(src + c * 8);
          f32x4 bb = *reinterpret_cast<const f32x4*>(src + c * 8 + 4);
          *reinterpret_cast<f32x4*>(dk + c * 8) = a;
          *reinterpret_cast<f32x4*>(dk + c * 8 + 4) = bb;
          short8 o;
#pragma unroll
          for (int j = 0; j < 4; j++) { o[j] = f2bf(a[j]); o[4 + j] = f2bf(bb[j]); }
          *reinterpret_cast<short8*>(dkb + c * 8) = o;
        }
      } else {
        float* dv = outv + base;
#pragma unroll
        for (int c = 0; c < 8; c++)
          *reinterpret_cast<f32x4*>(dv + c * 4) =
              *reinterpret_cast<const f32x4*>(src + c * 4);
      }
    }
  }
}

// Flash attention v15 (proven 46.5us) + T5 s_setprio around MFMA clusters.
// 4-wave block, 64 q-rows (16/wave), K+V shared dbuf LDS staging
// (lane-linear dest + pre-swizzled source), 4 B per q-k pair.
__global__ __launch_bounds__(256)
void flash_attn15(const short* __restrict__ qb, const short* __restrict__ kb,
                  const short* __restrict__ vtb, short* __restrict__ mb) {
  const int tid = threadIdx.x;
  const int w = tid >> 6, lane = tid & 63;
  const int r16 = lane & 15, g4 = lane >> 4;
  const int id = blockIdx.x;
  const int xcd = id & 7, u = id >> 3;        // u in [0,96)
  const int bh = xcd + 8 * (u % 3);
  const int qt = 31 - u / 3;                  // longest first
  const int q0 = qt * 64 + w * 16;            // this wave's 16 q-rows
  const int nkt = qt + 1;                     // 64-row KV tiles (uniform)

  const short* qh = qb + (long)bh * S_LEN * HD;
  const short* kh = kb + (long)bh * S_LEN * HD;
  const short* vh = vtb + (long)bh * S_LEN * HD;  // [32 kt][64 d][64 k]

  __shared__ __align__(16) short KVl[2][2][64][64];  // [buf][K|V][row][col] 32KB
  __shared__ __align__(16) short Pa[4][16][40];
  __shared__ __align__(16) short Pb[4][16][40];
  __shared__ __align__(16) float sca_lds[4][16];
  float* Olds = (float*)&KVl[0][0][0][0];            // [4][16][68] epilogue alias

  const int srow = tid >> 3, schunk = tid & 7;
  const short* ksrc = kh + srow * HD + ((schunk ^ (srow & 7)) * 8);
  const short* vsrc = vh + srow * 64 + ((schunk ^ (srow & 7)) * 8);
#define STAGE(BUF, KT) do {                                          \
    long _off = (long)(KT) * 4096;                                   \
    gload16(ksrc + _off,           &KVl[BUF][0][srow][schunk * 8]);      \
    gload16(ksrc + _off + 32 * HD, &KVl[BUF][0][srow + 32][schunk * 8]); \
    gload16(vsrc + _off,           &KVl[BUF][1][srow][schunk * 8]);      \
    gload16(vsrc + _off + 32 * 64, &KVl[BUF][1][srow + 32][schunk * 8]); \
  } while (0)

  short8 qf0 = *reinterpret_cast<const short8*>(qh + (q0 + r16) * HD + g4 * 8);
  short8 qf1 = *reinterpret_cast<const short8*>(qh + (q0 + r16) * HD + 32 + g4 * 8);

  float m0 = -1e30f, m20 = -1.44e30f;
  float l0 = 0.f;                             // per-lane partial row sum
  f32x4 oacc[4] = {};

  const int kc0 = (g4 ^ (r16 & 7)) * 8;       // swizzled chunk offset (shorts)

  STAGE(0, 0);

  for (int kt = 0; kt < nkt; kt++) {
    __syncthreads();  // drains stage (vmcnt) -> buf[kt&1] resident; readers synced
    if (kt + 1 < nkt) STAGE((kt + 1) & 1, kt + 1);

    const short* kbuf = &KVl[kt & 1][0][0][0];
    const short* vbuf = &KVl[kt & 1][1][0][0];

    short8 k00 = *reinterpret_cast<const short8*>(kbuf + (r16) * 64 + kc0);
    short8 k01 = *reinterpret_cast<const short8*>(kbuf + (r16) * 64 + (kc0 ^ 32));
    short8 k10 = *reinterpret_cast<const short8*>(kbuf + (16 + r16) * 64 + kc0);
    short8 k11 = *reinterpret_cast<const short8*>(kbuf + (16 + r16) * 64 + (kc0 ^ 32));
    short8 k20 = *reinterpret_cast<const short8*>(kbuf + (32 + r16) * 64 + kc0);
    short8 k21 = *reinterpret_cast<const short8*>(kbuf + (32 + r16) * 64 + (kc0 ^ 32));
    short8 k30 = *reinterpret_cast<const short8*>(kbuf + (48 + r16) * 64 + kc0);
    short8 k31 = *reinterpret_cast<const short8*>(kbuf + (48 + r16) * 64 + (kc0 ^ 32));

    f32x4 s0 = {0.f, 0.f, 0.f, 0.f}, s1 = {0.f, 0.f, 0.f, 0.f};
    f32x4 s2 = {0.f, 0.f, 0.f, 0.f}, s3 = {0.f, 0.f, 0.f, 0.f};
    __builtin_amdgcn_s_setprio(1);
    s0 = __builtin_amdgcn_mfma_f32_16x16x32_bf16(k00, qf0, s0, 0, 0, 0);
    s0 = __builtin_amdgcn_mfma_f32_16x16x32_bf16(k01, qf1, s0, 0, 0, 0);
    s1 = __builtin_amdgcn_mfma_f32_16x16x32_bf16(k10, qf0, s1, 0, 0, 0);
    s1 = __builtin_amdgcn_mfma_f32_16x16x32_bf16(k11, qf1, s1, 0, 0, 0);
    s2 = __builtin_amdgcn_mfma_f32_16x16x32_bf16(k20, qf0, s2, 0, 0, 0);
    s2 = __builtin_amdgcn_mfma_f32_16x16x32_bf16(k21, qf1, s2, 0, 0, 0);
    s3 = __builtin_amdgcn_mfma_f32_16x16x32_bf16(k30, qf0, s3, 0, 0, 0);
    s3 = __builtin_amdgcn_mfma_f32_16x16x32_bf16(k31, qf1, s3, 0, 0, 0);
    __builtin_amdgcn_s_setprio(0);

    if (kt == nkt - 1) {  // diagonal tile: mask k > q (global indices)
      int qg = q0 + r16;
#pragma unroll
      for (int r = 0; r < 4; r++) {
        int kbase = kt * 64 + g4 * 4 + r;
        if (kbase > qg)      s0[r] = -1e30f;
        if (kbase + 16 > qg) s1[r] = -1e30f;
        if (kbase + 32 > qg) s2[r] = -1e30f;
        if (kbase + 48 > qg) s3[r] = -1e30f;
      }
    }

    float rm_local = fmaxf(
        fmaxf(fmaxf(fmaxf(s0[0], s0[1]), fmaxf(s0[2], s0[3])),
              fmaxf(fmaxf(s1[0], s1[1]), fmaxf(s1[2], s1[3]))),
        fmaxf(fmaxf(fmaxf(s2[0], s2[1]), fmaxf(s2[2], s2[3])),
              fmaxf(fmaxf(s3[0], s3[1]), fmaxf(s3[2], s3[3]))));

    if (!__all(rm_local <= m0 + 8.f)) {
      float x = rm_local;
      x = fmaxf(x, __shfl_xor(x, 16));
      x = fmaxf(x, __shfl_xor(x, 32));
      float nm = fmaxf(m0, x);
      float sca = __builtin_exp2f((m0 - nm) * L2E);
      m0 = nm; m20 = nm * L2E; l0 *= sca;
      if (g4 == 0) sca_lds[w][r16] = sca;
      f32x4 sr = *reinterpret_cast<const f32x4*>(&sca_lds[w][g4 * 4]);
#pragma unroll
      for (int dt = 0; dt < 4; dt++)
#pragma unroll
        for (int r = 0; r < 4; r++) oacc[dt][r] *= sr[r];
    }

    float rs = 0.f;
#pragma unroll
    for (int r = 0; r < 4; r++) {
      s0[r] = __builtin_exp2f(fmaf(s0[r], L2E, -m20));
      s1[r] = __builtin_exp2f(fmaf(s1[r], L2E, -m20));
      s2[r] = __builtin_exp2f(fmaf(s2[r], L2E, -m20));
      s3[r] = __builtin_exp2f(fmaf(s3[r], L2E, -m20));
      rs += (s0[r] + s1[r]) + (s2[r] + s3[r]);
    }
    l0 += rs;

    {
      uint2 wv;
      wv.x = pkbf(s0[0], s0[1]); wv.y = pkbf(s0[2], s0[3]);
      *reinterpret_cast<uint2*>(&Pa[w][r16][g4 * 4]) = wv;
      wv.x = pkbf(s1[0], s1[1]); wv.y = pkbf(s1[2], s1[3]);
      *reinterpret_cast<uint2*>(&Pa[w][r16][16 + g4 * 4]) = wv;
      wv.x = pkbf(s2[0], s2[1]); wv.y = pkbf(s2[2], s2[3]);
      *reinterpret_cast<uint2*>(&Pb[w][r16][g4 * 4]) = wv;
      wv.x = pkbf(s3[0], s3[1]); wv.y = pkbf(s3[2], s3[3]);
      *reinterpret_cast<uint2*>(&Pb[w][r16][16 + g4 * 4]) = wv;
    }
    short8 pa0 = *reinterpret_cast<const short8*>(&Pa[w][r16][g4 * 8]);
    short8 pa1 = *reinterpret_cast<const short8*>(&Pb[w][r16][g4 * 8]);

    short8 v00 = *reinterpret_cast<const short8*>(vbuf + (r16) * 64 + kc0);
    short8 v01 = *reinterpret_cast<const short8*>(vbuf + (r16) * 64 + (kc0 ^ 32));
    short8 v10 = *reinterpret_cast<const short8*>(vbuf + (16 + r16) * 64 + kc0);
    short8 v11 = *reinterpret_cast<const short8*>(vbuf + (16 + r16) * 64 + (kc0 ^ 32));
    short8 v20 = *reinterpret_cast<const short8*>(vbuf + (32 + r16) * 64 + kc0);
    short8 v21 = *reinterpret_cast<const short8*>(vbuf + (32 + r16) * 64 + (kc0 ^ 32));
    short8 v30 = *reinterpret_cast<const short8*>(vbuf + (48 + r16) * 64 + kc0);
    short8 v31 = *reinterpret_cast<const short8*>(vbuf + (48 + r16) * 64 + (kc0 ^ 32));

    __builtin_amdgcn_s_setprio(1);
    oacc[0] = __builtin_amdgcn_mfma_f32_16x16x32_bf16(pa0, v00, oacc[0], 0, 0, 0);
    oacc[0] = __builtin_amdgcn_mfma_f32_16x16x32_bf16(pa1, v01, oacc[0], 0, 0, 0);
    oacc[1] = __builtin_amdgcn_mfma_f32_16x16x32_bf16(pa0, v10, oacc[1], 0, 0, 0);
    oacc[1] = __builtin_amdgcn_mfma_f32_16x16x32_bf16(pa1, v11, oacc[1], 0, 0, 0);
    oacc[2] = __builtin_amdgcn_mfma_f32_16x16x32_bf16(pa0, v20, oacc[2], 0, 0, 0);
    oacc[2] = __builtin_amdgcn_mfma_f32_16x16x32_bf16(pa1, v21, oacc[2], 0, 0, 0);
    oacc[3] = __builtin_amdgcn_mfma_f32_16x16x32_bf16(pa0, v30, oacc[3], 0, 0, 0);
    oacc[3] = __builtin_amdgcn_mfma_f32_16x16x32_bf16(pa1, v31, oacc[3], 0, 0, 0);
    __builtin_amdgcn_s_setprio(0);
  }
#undef STAGE

  __syncthreads();  // all waves done with KVl before Olds aliasing

  {
    float rs = l0;
    rs += __shfl_xor(rs, 16);
    rs += __shfl_xor(rs, 32);
    if (g4 == 0) sca_lds[w][r16] = rs;
  }
  f32x4 li = *reinterpret_cast<const f32x4*>(&sca_lds[w][g4 * 4]);
  f32x4 iv;
#pragma unroll
  for (int r = 0; r < 4; r++) iv[r] = 1.f / li[r];
  float* Ow = Olds + w * 16 * 68;
#pragma unroll
  for (int dt = 0; dt < 4; dt++)
#pragma unroll
    for (int r = 0; r < 4; r++)
      Ow[(g4 * 4 + r) * 68 + dt * 16 + r16] = oacc[dt][r] * iv[r];
  {
    int orow = lane >> 2, oc = (lane & 3) * 16;
    int bb = bh / NH, h = bh % NH;
    f32x4 a0 = *reinterpret_cast<const f32x4*>(&Ow[orow * 68 + oc]);
    f32x4 a1 = *reinterpret_cast<const f32x4*>(&Ow[orow * 68 + oc + 4]);
    f32x4 a2 = *reinterpret_cast<const f32x4*>(&Ow[orow * 68 + oc + 8]);
    f32x4 a3 = *reinterpret_cast<const f32x4*>(&Ow[orow * 68 + oc + 12]);
    short8 sa, sb;
#pragma unroll
    for (int j = 0; j < 4; j++) {
      sa[j] = f2bf(a0[j]); sa[4 + j] = f2bf(a1[j]);
      sb[j] = f2bf(a2[j]); sb[4 + j] = f2bf(a3[j]);
    }
    short* dst = &mb[((long)(bb * S_LEN + q0 + orow)) * EMB + h * HD + oc];
    *reinterpret_cast<short8*>(dst) = sa;
    *reinterpret_cast<short8*>(dst + 8) = sb;
  }
}

extern "C" void kernel_launch(void* const* d_in, const int* in_sizes, int n_in,
                              void* d_out, int out_size, void* d_ws, size_t ws_size,
                              hipStream_t stream) {
  const float* x  = (const float*)d_in[0];
  const float* Wq = (const float*)d_in[1];
  const float* Wk = (const float*)d_in[2];
  const float* Wv = (const float*)d_in[3];
  const float* Wo = (const float*)d_in[4];
  const float* bo = (const float*)d_in[5];

  float* out  = (float*)d_out;
  float* outk = out + 3145728;
  float* outv = out + 6291456;

  short* ws  = (short*)d_ws;
  short* xb  = ws;                 // [4096][768]
  short* Wb  = xb + 3145728;       // [2304][768]  (Wq;Wk;Wv)
  short* Wob = Wb + 1769472;       // [768][768]
  short* qb  = Wob + 589824;       // [24][2048][64]
  short* kb  = qb + 3145728;       // [24][2048][64]
  short* vtb = kb + 3145728;       // [24][32][64][64]  (V tiled per 64-row KV tile)
  short* mb  = vtb + 3145728;      // [4096][768]    merged attn, bf16

  cvt_all<<<5376, 256, 0, stream>>>(x, Wq, Wk, Wv, Wo, xb, Wb, Wob);

  gemm_nt<0><<<dim3(18, 32), 256, 0, stream>>>(xb, Wb, outk, outv, qb, kb, vtb, nullptr, nullptr);
  flash_attn15<<<768, 256, 0, stream>>>(qb, kb, vtb, mb);
  gemm_nt<1><<<dim3(6, 32), 256, 0, stream>>>(mb, Wob, nullptr, nullptr, nullptr, nullptr, nullptr, out, bo);
}